// Round 10
// baseline (342.146 us; speedup 1.0000x reference)
//
#include <hip/hip_runtime.h>

// ---------------------------------------------------------------------------
// equinet F* pipeline on MI355X.
// R10: butterfly layers re-expressed as per-unit 72x72 operators applied with
// fp16 MFMA (16x16x32). G built in-kernel (fp32 LDS -> f16), X staged to LDS
// with perm fused. Composites: V+H1 -> 72x32; switch+M1..M3+G1 -> one 72x72.
// State stays f16 [row][batch]. GEMM/transpose/gather/u unchanged from R9.
// ---------------------------------------------------------------------------

typedef _Float16 f16;
typedef __attribute__((ext_vector_type(8))) _Float16 hx8;
typedef __attribute__((ext_vector_type(8))) short sx8;
typedef __attribute__((ext_vector_type(4))) float fx4;
typedef __attribute__((ext_vector_type(8))) unsigned short usx8;
typedef __attribute__((ext_vector_type(4))) unsigned short usx4;

__device__ __forceinline__ unsigned short f2bf(float f) {
  unsigned u = __builtin_bit_cast(unsigned, f);
  u = (u + 0x7FFFu + ((u >> 16) & 1u)) >> 16;
  return (unsigned short)u;
}
__device__ __forceinline__ float bf2f(unsigned short h) {
  return __builtin_bit_cast(float, ((unsigned)h) << 16);
}

// Permutation ids: 0=identity, 1=perm(l=4), 2=perm(l=3), 3=switch, 4=perm(l=2),
// 5=perm(l=1), 6=perm(l=0).
template<int ID>
__device__ __forceinline__ int rp_apply(int k) {
  if constexpr (ID == 0) { return k; }
  else if constexpr (ID == 3) { return (k & 7) * 8 + (k >> 3); }
  else {
    constexpr int l = (ID == 1) ? 4 : (ID == 2) ? 3 : (ID == 4) ? 2 : (ID == 5) ? 1 : 0;
    constexpr int d = 1 << (5 - l);
    constexpr int m2 = 2 * d;
    int g = k / m2, r = k % m2;
    return g * m2 + (r & 1) * d + (r >> 1);
  }
}

// quadrant (c_out, c_in) -> term tt's (lm, rm) per the reference's 8 products
__device__ __forceinline__ void qterm(int co, int ci, int tt, int& lm, int& rm) {
  if (!co && !ci) { lm = tt;     rm = tt;     }
  else if (!co)   { lm = 2 + tt; rm = 3 - tt; }   // Yr from Xi: (2,3),(3,2)
  else if (!ci)   { lm = 6 + tt; rm = 7 - tt; }   // Yi from Xr: (6,7),(7,6)
  else            { lm = 4 + tt; rm = 4 + tt; }   // Yi from Xi: (4,4),(5,5)
}

// ---------------------------------------------------------------------------
// Shared MFMA core: Y(72x128) = G(72xK)·X(Kx128), K = NKC*32.
// G in LDS f16 [80][GP] (rows/cols >=72 zero); X in LDS f16 [NKC*32][136].
// 256 threads = 4 waves; wave w covers batch cols [w*32, w*32+32).
// ---------------------------------------------------------------------------
template<int NKC, int GP>
__device__ __forceinline__ void lay_mfma(const f16* Gl, const f16* Xl,
                                         int P, int Q, int t,
                                         f16* __restrict__ yr,
                                         f16* __restrict__ yi) {
  const int w = t >> 6, lane = t & 63;
  const int lrow = lane & 15, lgr = lane >> 4;
  fx4 acc[5][2];
#pragma unroll
  for (int mt = 0; mt < 5; ++mt) { acc[mt][0] = (fx4)0.f; acc[mt][1] = (fx4)0.f; }
#pragma unroll
  for (int kc = 0; kc < NKC; ++kc) {
    hx8 af[5], bf[2];
#pragma unroll
    for (int mt = 0; mt < 5; ++mt)
      af[mt] = *(const hx8*)(Gl + (mt * 16 + lrow) * GP + kc * 32 + lgr * 8);
#pragma unroll
    for (int nt2 = 0; nt2 < 2; ++nt2) {
      int n = (2 * w + nt2) * 16 + lrow;
      int k0 = kc * 32 + lgr * 8;
      hx8 b;
#pragma unroll
      for (int j = 0; j < 8; ++j) b[j] = Xl[(k0 + j) * 136 + n];
      bf[nt2] = b;
    }
#pragma unroll
    for (int mt = 0; mt < 5; ++mt)
#pragma unroll
      for (int nt2 = 0; nt2 < 2; ++nt2)
        acc[mt][nt2] = __builtin_amdgcn_mfma_f32_16x16x32_f16(af[mt], bf[nt2], acc[mt][nt2], 0, 0, 0);
  }
#pragma unroll
  for (int mt = 0; mt < 5; ++mt)
#pragma unroll
    for (int nt2 = 0; nt2 < 2; ++nt2)
#pragma unroll
      for (int r = 0; r < 4; ++r) {
        int row = mt * 16 + lgr * 4 + r;
        if (row >= 72) continue;
        int n = (2 * w + nt2) * 16 + lrow;
        int c = row >= 36;
        int s = row - c * 36;
        size_t off = ((size_t)((P * 6 + s / 6) * 192 + (Q * 6 + s % 6))) * 128 + n;
        (c ? yi : yr)[off] = (f16)acc[mt][nt2][r];
      }
}

// ---------------------------------------------------------------------------
// Transpose x (B,128,128,2) fp32 -> xtr/xti (16384, 128) fp16  (unchanged R9)
// ---------------------------------------------------------------------------
__global__ __launch_bounds__(256) void k_transpose(const float* __restrict__ x,
                                                   f16* __restrict__ xtr,
                                                   f16* __restrict__ xti) {
  __shared__ float ls[2][32][129];
  const int t = threadIdx.x;
  const int u = blockIdx.x;
  const int v0 = blockIdx.y * 32;
  for (int it = 0; it < 32; ++it) {
    int b = it * 4 + (t >> 6);
    int r = t & 63;
    int v = r >> 1, ch = r & 1;
    ls[ch][v][b] = x[(((size_t)b * 128 + u) * 128 + (v0 + v)) * 2 + ch];
  }
  __syncthreads();
  for (int it = 0; it < 32; ++it) {
    int idx = it * 256 + t;
    int ch = idx >> 12;
    int v = (idx >> 7) & 31;
    int b = idx & 127;
    f16* dst = ch ? xti : xtr;
    dst[((size_t)(u * 128 + v0 + v)) * 128 + b] = (f16)ls[ch][v][b];
  }
}

// ---------------------------------------------------------------------------
// H/G-type layer as MFMA: wp (8,32,6,6).  Grid (32,32), 256 thr.
// ---------------------------------------------------------------------------
template<int PERM>
__global__ __launch_bounds__(256) void k_lay(const f16* __restrict__ xr,
                                             const f16* __restrict__ xi,
                                             f16* __restrict__ yr,
                                             f16* __restrict__ yi,
                                             const float* __restrict__ wp) {
  __shared__ float Wl[8][36], Wr[8][36];
  __shared__ __align__(16) f16 Gl[80 * 104];
  __shared__ __align__(16) f16 Xl[96 * 136];
  const int t = threadIdx.x;
  const int P = blockIdx.x, Q = blockIdx.y;
  for (int idx = t; idx < 288; idx += 256) {
    int lm = idx / 36, e = idx % 36;
    Wl[lm][e] = wp[((size_t)lm * 32 + P) * 36 + e];
    Wr[lm][e] = wp[((size_t)lm * 32 + Q) * 36 + e];
  }
  __syncthreads();
  // build G: G[(co,O,K2)][(ci,I,J)] = sum_terms Lw[I*6+O]*Rw[J*6+K2]
  for (int idx = t; idx < 80 * 104; idx += 256) {
    int u = idx / 104, v = idx % 104;
    float g = 0.f;
    if (u < 72 && v < 72) {
      int co = u / 36, ru = u % 36, O = ru / 6, K2 = ru % 6;
      int ci = v / 36, sv = v % 36, I = sv / 6, J = sv % 6;
      int lm0, rm0, lm1, rm1;
      qterm(co, ci, 0, lm0, rm0);
      qterm(co, ci, 1, lm1, rm1);
      g = Wl[lm0][I * 6 + O] * Wr[rm0][J * 6 + K2]
        + Wl[lm1][I * 6 + O] * Wr[rm1][J * 6 + K2];
    }
    Gl[idx] = (f16)g;
  }
  // stage X (rows >=72 zeroed)
  for (int idx = t; idx < 96 * 16; idx += 256) {
    int row = idx / 16, seg = idx % 16;
    usx8 v = (usx8)((unsigned short)0);
    if (row < 72) {
      int c = row / 36, sv = row % 36, I = sv / 6, J = sv % 6;
      int grow = rp_apply<PERM>(2 * P + I / 3) * 3 + I % 3;
      int gcol = rp_apply<PERM>(2 * Q + J / 3) * 3 + J % 3;
      const unsigned short* src = (const unsigned short*)(c ? xi : xr);
      v = *(const usx8*)(src + (size_t)(grow * 192 + gcol) * 128 + seg * 8);
    }
    *(usx8*)((unsigned short*)Xl + row * 136 + seg * 8) = v;
  }
  __syncthreads();
  lay_mfma<3, 104>(Gl, Xl, P, Q, t, yr, yi);
}

// ---------------------------------------------------------------------------
// V+H1 as MFMA: G_vh(72x32) = H1_72 * blkdiag(Vq).  vp (8,64,2,3), hp (8,32,36)
// ---------------------------------------------------------------------------
__global__ __launch_bounds__(256) void k_vhm(const f16* __restrict__ xtr,
                                             const f16* __restrict__ xti,
                                             f16* __restrict__ yr,
                                             f16* __restrict__ yi,
                                             const float* __restrict__ vp,
                                             const float* __restrict__ hp) {
  __shared__ float Wl[8][36], Wr[8][36];
  __shared__ float Vl[8][2][6], Vr[8][2][6];
  __shared__ float H72[72 * 72];
  __shared__ float Vq[4][18][8];
  __shared__ __align__(16) f16 Gv[80 * 40];
  __shared__ __align__(16) f16 Xv[32 * 136];
  const int t = threadIdx.x;
  const int P = blockIdx.x, Q = blockIdx.y;
  for (int idx = t; idx < 288; idx += 256) {
    int lm = idx / 36, e = idx % 36;
    Wl[lm][e] = hp[((size_t)lm * 32 + P) * 36 + e];
    Wr[lm][e] = hp[((size_t)lm * 32 + Q) * 36 + e];
  }
  for (int idx = t; idx < 96; idx += 256) {
    int lm = idx / 12, r = idx % 12, aa = r / 6, e = r % 6;
    Vl[lm][aa][e] = vp[((size_t)lm * 64 + (2 * P + aa)) * 6 + e];
    Vr[lm][aa][e] = vp[((size_t)lm * 64 + (2 * Q + aa)) * 6 + e];
  }
  __syncthreads();
  for (int idx = t; idx < 72 * 72; idx += 256) {
    int u = idx / 72, v = idx % 72;
    int co = u / 36, ru = u % 36, O = ru / 6, K2 = ru % 6;
    int ci = v / 36, sv = v % 36, I = sv / 6, J = sv % 6;
    int lm0, rm0, lm1, rm1;
    qterm(co, ci, 0, lm0, rm0);
    qterm(co, ci, 1, lm1, rm1);
    H72[idx] = Wl[lm0][I * 6 + O] * Wr[rm0][J * 6 + K2]
             + Wl[lm1][I * 6 + O] * Wr[rm1][J * 6 + K2];
  }
  for (int idx = t; idx < 4 * 18 * 8; idx += 256) {
    int s = idx / 144, r = idx % 144, a = r / 8, b = r % 8;
    int ca = a / 9, ra = a % 9, o = ra / 3, k3 = ra % 3;
    int cb = b >> 2, i2 = (b >> 1) & 1, j2 = b & 1;
    int aa = s >> 1, bb = s & 1;
    int lm0, rm0, lm1, rm1;
    qterm(ca, cb, 0, lm0, rm0);
    qterm(ca, cb, 1, lm1, rm1);
    Vq[s][a][b] = Vl[lm0][aa][i2 * 3 + o] * Vr[rm0][bb][j2 * 3 + k3]
                + Vl[lm1][aa][i2 * 3 + o] * Vr[rm1][bb][j2 * 3 + k3];
  }
  __syncthreads();
  for (int idx = t; idx < 80 * 40; idx += 256) {
    int u = idx / 40, v = idx % 40;
    float g = 0.f;
    if (u < 72 && v < 32) {
      int s = v >> 3, aa = s >> 1, bb = s & 1;
      int c = (v >> 2) & 1, i2 = (v >> 1) & 1, j2 = v & 1;
#pragma unroll
      for (int cw = 0; cw < 2; ++cw)
#pragma unroll
        for (int o = 0; o < 3; ++o)
#pragma unroll
          for (int k3 = 0; k3 < 3; ++k3)
            g += H72[u * 72 + cw * 36 + (3 * aa + o) * 6 + (3 * bb + k3)]
               * Vq[s][cw * 9 + o * 3 + k3][c * 4 + i2 * 2 + j2];
    }
    Gv[idx] = (f16)g;
  }
  for (int idx = t; idx < 32 * 16; idx += 256) {
    int row = idx / 16, seg = idx % 16;
    int s = row >> 3, aa = s >> 1, bb = s & 1;
    int c = (row >> 2) & 1, i2 = (row >> 1) & 1, j2 = row & 1;
    const unsigned short* src = (const unsigned short*)(c ? xti : xtr);
    usx8 v = *(const usx8*)(src + (size_t)((4 * P + 2 * aa + i2) * 128 + (4 * Q + 2 * bb + j2)) * 128 + seg * 8);
    *(usx8*)((unsigned short*)Xv + row * 136 + seg * 8) = v;
  }
  __syncthreads();
  lay_mfma<1, 40>(Gv, Xv, P, Q, t, yr, yi);
}

// ---------------------------------------------------------------------------
// switch + M1..M3 + G1 as one 72x72 operator. mp (3,8,64,3,3), gp (8,32,36).
// ---------------------------------------------------------------------------
__global__ __launch_bounds__(256) void k_mgm(const f16* __restrict__ xr,
                                             const f16* __restrict__ xi,
                                             f16* __restrict__ yr,
                                             f16* __restrict__ yi,
                                             const float* __restrict__ mp,
                                             const float* __restrict__ gp) {
  __shared__ __align__(16) char sm[58688];
  float (*Ml)[8][2][9] = (float (*)[8][2][9])(sm + 0);       // [3][8][2][9]
  float (*Mr)[8][2][9] = (float (*)[8][2][9])(sm + 1728);
  float (*Wl)[36]      = (float (*)[36])(sm + 3456);         // [8][36]
  float (*Wr)[36]      = (float (*)[36])(sm + 4608);
  float (*C)[18][18]   = (float (*)[18][18])(sm + 5760);     // [4][18][18]
  float (*T)[18][18]   = (float (*)[18][18])(sm + 10944);
  float (*D)[18][18]   = (float (*)[18][18])(sm + 16128);
  float* G1            = (float*)(sm + 21312);               // [72*72]
  f16*   Gm            = (f16*)(sm + 42048);                 // [80*104]
  f16*   Xm            = (f16*)(sm + 0);                     // [96*136] (phase F)
  const int t = threadIdx.x;
  const int P = blockIdx.x, Q = blockIdx.y;

  for (int idx = t; idx < 432; idx += 256) {
    int lk = idx / 144, r0 = idx % 144, lm = r0 / 18, r1 = r0 % 18, aa = r1 / 9, e = r1 % 9;
    Ml[lk][lm][aa][e] = mp[(((size_t)lk * 8 + lm) * 64 + (2 * P + aa)) * 9 + e];
    Mr[lk][lm][aa][e] = mp[(((size_t)lk * 8 + lm) * 64 + (2 * Q + aa)) * 9 + e];
  }
  for (int idx = t; idx < 288; idx += 256) {
    int lm = idx / 36, e = idx % 36;
    Wl[lm][e] = gp[((size_t)lm * 32 + P) * 36 + e];
    Wr[lm][e] = gp[((size_t)lm * 32 + Q) * 36 + e];
  }
  __syncthreads();
  // build I+Mk into OUT
  auto buildIM = [&](int lk, float (*OUT)[18][18]) {
    for (int idx = t; idx < 4 * 324; idx += 256) {
      int s = idx / 324, r = idx % 324, a = r / 18, b = r % 18;
      int ca = a / 9, ra = a % 9, o = ra / 3, k3 = ra % 3;
      int cb = b / 9, rb = b % 9, i = rb / 3, j = rb % 3;
      int aa = s >> 1, bb = s & 1;
      int lm0, rm0, lm1, rm1;
      qterm(ca, cb, 0, lm0, rm0);
      qterm(ca, cb, 1, lm1, rm1);
      float val = Ml[lk][lm0][aa][i * 3 + o] * Mr[lk][rm0][bb][j * 3 + k3]
                + Ml[lk][lm1][aa][i * 3 + o] * Mr[lk][rm1][bb][j * 3 + k3];
      if (a == b) val += 1.f;
      OUT[s][a][b] = val;
    }
  };
  auto matmul18 = [&](float (*OUT)[18][18], float (*A)[18][18], float (*B)[18][18]) {
    for (int idx = t; idx < 4 * 324; idx += 256) {
      int s = idx / 324, r = idx % 324, a = r / 18, b = r % 18;
      float acc = 0.f;
#pragma unroll
      for (int c18 = 0; c18 < 18; ++c18) acc += A[s][a][c18] * B[s][c18][b];
      OUT[s][a][b] = acc;
    }
  };
  // phase A: C = I+M0, T = I+M1, G1 build
  buildIM(0, C);
  buildIM(1, T);
  for (int idx = t; idx < 72 * 72; idx += 256) {
    int u = idx / 72, v = idx % 72;
    int co = u / 36, ru = u % 36, O = ru / 6, K2 = ru % 6;
    int ci = v / 36, sv = v % 36, I = sv / 6, J = sv % 6;
    int lm0, rm0, lm1, rm1;
    qterm(co, ci, 0, lm0, rm0);
    qterm(co, ci, 1, lm1, rm1);
    G1[idx] = Wl[lm0][I * 6 + O] * Wr[rm0][J * 6 + K2]
            + Wl[lm1][I * 6 + O] * Wr[rm1][J * 6 + K2];
  }
  __syncthreads();
  matmul18(D, T, C);       // D = (I+M1)(I+M0)
  __syncthreads();
  buildIM(2, T);           // T = I+M2
  __syncthreads();
  matmul18(C, T, D);       // C = (I+M2)(I+M1)(I+M0)
  __syncthreads();
  // phase E: Gm = G1 * blkdiag-expand(C)
  for (int idx = t; idx < 80 * 104; idx += 256) {
    int u = idx / 104, v = idx % 104;
    float g = 0.f;
    if (u < 72 && v < 72) {
      int cv = v / 36, sv = v % 36, I = sv / 6, J = sv % 6;
      int aa = I / 3, bb = J / 3, i = I % 3, j = J % 3;
      int s = aa * 2 + bb, v18 = cv * 9 + i * 3 + j;
#pragma unroll
      for (int cw = 0; cw < 2; ++cw)
#pragma unroll
        for (int i2 = 0; i2 < 3; ++i2)
#pragma unroll
          for (int j2 = 0; j2 < 3; ++j2)
            g += G1[u * 72 + cw * 36 + (3 * aa + i2) * 6 + (3 * bb + j2)]
               * C[s][cw * 9 + i2 * 3 + j2][v18];
    }
    Gm[idx] = (f16)g;
  }
  __syncthreads();
  // phase F: stage X with switch perm (overlays dead fp32 regions)
  for (int idx = t; idx < 96 * 16; idx += 256) {
    int row = idx / 16, seg = idx % 16;
    usx8 v = (usx8)((unsigned short)0);
    if (row < 72) {
      int c = row / 36, sv = row % 36, I = sv / 6, J = sv % 6;
      int grow = rp_apply<3>(2 * P + I / 3) * 3 + I % 3;
      int gcol = rp_apply<3>(2 * Q + J / 3) * 3 + J % 3;
      const unsigned short* src = (const unsigned short*)(c ? xi : xr);
      v = *(const usx8*)(src + (size_t)(grow * 192 + gcol) * 128 + seg * 8);
    }
    *(usx8*)((unsigned short*)Xm + row * 136 + seg * 8) = v;
  }
  __syncthreads();
  lay_mfma<3, 104>(Gm, Xm, P, Q, t, yr, yi);
}

// ---------------------------------------------------------------------------
// U layer (unchanged R9). perm(l=0) on read. Up:(8,64,3,2)
// ---------------------------------------------------------------------------
__global__ __launch_bounds__(128, 2) void k_u(const f16* __restrict__ xr,
                                              const f16* __restrict__ xi,
                                              unsigned short* __restrict__ ut,
                                              const float* __restrict__ wp) {
  const int b = threadIdx.x;
  const int p = blockIdx.x, q = blockIdx.y;
  int rrow[3], rcol[3];
#pragma unroll
  for (int i = 0; i < 3; ++i) {
    rrow[i] = rp_apply<6>(p) * 3 + i;
    rcol[i] = rp_apply<6>(q) * 3 + i;
  }
  float X[9], Y[4] = {0.f, 0.f, 0.f, 0.f};
  auto loadX = [&](const f16* src) {
#pragma unroll
    for (int i = 0; i < 3; ++i)
#pragma unroll
      for (int j = 0; j < 3; ++j)
        X[i * 3 + j] = (float)src[((size_t)(rrow[i] * 192 + rcol[j])) * 128 + b];
  };
  auto term = [&](int lm, int rm) {
    const float* Lw = wp + ((size_t)lm * 64 + p) * 6;
    const float* Rw = wp + ((size_t)rm * 64 + q) * 6;
#pragma unroll
    for (int i = 0; i < 3; ++i) {
      float t0 = X[i*3+0] * Rw[0] + X[i*3+1] * Rw[2] + X[i*3+2] * Rw[4];
      float t1 = X[i*3+0] * Rw[1] + X[i*3+1] * Rw[3] + X[i*3+2] * Rw[5];
      Y[0] += Lw[i*2+0] * t0; Y[1] += Lw[i*2+0] * t1;
      Y[2] += Lw[i*2+1] * t0; Y[3] += Lw[i*2+1] * t1;
    }
  };
  loadX(xr); term(0, 0); term(3, 3);
  loadX(xi); term(4, 5); term(7, 6);
#pragma unroll
  for (int o = 0; o < 2; ++o)
#pragma unroll
    for (int k = 0; k < 2; ++k)
      ut[((size_t)((p * 2 + o) * 128 + (q * 2 + k))) * 128 + b] = f2bf(Y[o * 2 + k]);
}

// ---------------------------------------------------------------------------
// Gather + transpose (unchanged R9)
// ---------------------------------------------------------------------------
__global__ __launch_bounds__(256) void k_gather(const unsigned short* __restrict__ ut,
                                                const int* __restrict__ r_index,
                                                unsigned short* __restrict__ yg) {
  __shared__ unsigned short ls[64][130];
  __shared__ int ridx[64];
  const int t = threadIdx.x;
  const int m0 = blockIdx.x * 64;
  if (t < 64) ridx[t] = r_index[m0 + t];
  __syncthreads();
  for (int it = 0; it < 32; ++it) {
    int idx = it * 256 + t;
    int ml = idx >> 7, b = idx & 127;
    ls[ml][b] = ut[(size_t)ridx[ml] * 128 + b];
  }
  __syncthreads();
  int b = t >> 1, half = t & 1;
#pragma unroll
  for (int c = 0; c < 4; ++c) {
    usx8 v;
#pragma unroll
    for (int e = 0; e < 8; ++e) v[e] = ls[half * 32 + c * 8 + e][b];
    *(usx8*)(yg + (size_t)b * 16384 + m0 + half * 32 + c * 8) = v;
  }
}

// ---------------------------------------------------------------------------
// GEMM (unchanged R8/R9): grid (8,100), BK=64, bf16 partial.
// ---------------------------------------------------------------------------
#define G2_KC 8
#define G2_STEPS 32
#define G2_PITCH 72

__global__ __launch_bounds__(256) void k_gemm2(const unsigned short* __restrict__ yg,
                                               const float* __restrict__ cart,
                                               unsigned short* __restrict__ partial) {
  __shared__ unsigned short As[2][128][G2_PITCH];
  __shared__ unsigned short Bs[2][64][G2_PITCH];
  const int t = threadIdx.x;
  const int lane = t & 63, w = t >> 6;
  const int kc = blockIdx.x;
  const int c0 = blockIdx.y * 64;
  const int k0 = kc * 2048;

  fx4 acc[2][4];
#pragma unroll
  for (int i = 0; i < 2; ++i)
#pragma unroll
    for (int j = 0; j < 4; ++j) acc[i][j] = (fx4)0.f;

  auto ldA = [&](int rep, int kpos) -> usx8 {
    int c = t + rep * 256;
    return *(const usx8*)(yg + (size_t)(c >> 3) * 16384 + kpos + (c & 7) * 8);
  };
  auto stA = [&](int buf, int rep, usx8 v) {
    int c = t + rep * 256;
    *(usx8*)(&As[buf][c >> 3][(c & 7) * 8]) = v;
  };
  auto ldB = [&](int rep, int kpos, fx4* f0, fx4* f1) {
    int c = t + rep * 256;
    const float* p = cart + (size_t)(c0 + (c >> 3)) * 16384 + kpos + (c & 7) * 8;
    *f0 = *(const fx4*)p;
    *f1 = *(const fx4*)(p + 4);
  };
  auto stB = [&](int buf, int rep, fx4 f0, fx4 f1) {
    int c = t + rep * 256;
    usx8 v;
    v[0]=f2bf(f0[0]); v[1]=f2bf(f0[1]); v[2]=f2bf(f0[2]); v[3]=f2bf(f0[3]);
    v[4]=f2bf(f1[0]); v[5]=f2bf(f1[1]); v[6]=f2bf(f1[2]); v[7]=f2bf(f1[3]);
    *(usx8*)(&Bs[buf][c >> 3][(c & 7) * 8]) = v;
  };

  {
    usx8 a0 = ldA(0, k0), a1 = ldA(1, k0), a2 = ldA(2, k0), a3 = ldA(3, k0);
    fx4 b00, b01, b10, b11;
    ldB(0, k0, &b00, &b01); ldB(1, k0, &b10, &b11);
    stA(0, 0, a0); stA(0, 1, a1); stA(0, 2, a2); stA(0, 3, a3);
    stB(0, 0, b00, b01); stB(0, 1, b10, b11);
  }
  __syncthreads();

  for (int s = 0; s < G2_STEPS; ++s) {
    const int cur = s & 1;
    usx8 av[4]; fx4 b00, b01, b10, b11;
    const bool pf = (s + 1 < G2_STEPS);
    if (pf) {
      int kpos = k0 + (s + 1) * 64;
      av[0] = ldA(0, kpos); av[1] = ldA(1, kpos);
      av[2] = ldA(2, kpos); av[3] = ldA(3, kpos);
      ldB(0, kpos, &b00, &b01); ldB(1, kpos, &b10, &b11);
    }
    sx8 af[2][2], bf[4][2];
#pragma unroll
    for (int mi = 0; mi < 2; ++mi)
#pragma unroll
      for (int kk = 0; kk < 2; ++kk)
        af[mi][kk] = *(const sx8*)(&As[cur][w * 32 + mi * 16 + (lane & 15)][kk * 32 + (lane >> 4) * 8]);
#pragma unroll
    for (int ni = 0; ni < 4; ++ni)
#pragma unroll
      for (int kk = 0; kk < 2; ++kk)
        bf[ni][kk] = *(const sx8*)(&Bs[cur][ni * 16 + (lane & 15)][kk * 32 + (lane >> 4) * 8]);
#pragma unroll
    for (int kk = 0; kk < 2; ++kk)
#pragma unroll
      for (int mi = 0; mi < 2; ++mi)
#pragma unroll
        for (int ni = 0; ni < 4; ++ni)
          acc[mi][ni] = __builtin_amdgcn_mfma_f32_16x16x32_bf16(af[mi][kk], bf[ni][kk], acc[mi][ni], 0, 0, 0);
    if (pf) {
      stA(cur ^ 1, 0, av[0]); stA(cur ^ 1, 1, av[1]);
      stA(cur ^ 1, 2, av[2]); stA(cur ^ 1, 3, av[3]);
      stB(cur ^ 1, 0, b00, b01); stB(cur ^ 1, 1, b10, b11);
    }
    __syncthreads();
  }

#pragma unroll
  for (int mi = 0; mi < 2; ++mi) {
    int brow = w * 32 + mi * 16 + (lane >> 4) * 4;
#pragma unroll
    for (int ni = 0; ni < 4; ++ni) {
      int cc = c0 + ni * 16 + (lane & 15);
#pragma unroll
      for (int r = 0; r < 4; ++r)
        partial[((size_t)kc * 128 + brow + r) * 6400 + cc] = f2bf(acc[mi][ni][r]);
    }
  }
}

__global__ __launch_bounds__(256) void k_reduce2(const unsigned short* __restrict__ partial,
                                                 float* __restrict__ out) {
  int i = blockIdx.x * 256 + threadIdx.x;
  fx4 s = (fx4)0.f;
#pragma unroll
  for (int kc = 0; kc < G2_KC; ++kc) {
    usx4 v = *(const usx4*)(partial + (size_t)kc * 819200 + (size_t)i * 4);
    s[0] += bf2f(v[0]); s[1] += bf2f(v[1]); s[2] += bf2f(v[2]); s[3] += bf2f(v[3]);
  }
  *(fx4*)(out + (size_t)i * 4) = s;
}

// ---------------------------------------------------------------------------
extern "C" void kernel_launch(void* const* d_in, const int* in_sizes, int n_in,
                              void* d_out, int out_size, void* d_ws, size_t ws_size,
                              hipStream_t stream) {
  const float* x    = (const float*)d_in[0];
  const float* Vp   = (const float*)d_in[1];
  const float* Hp   = (const float*)d_in[2];
  const float* Mp   = (const float*)d_in[3];
  const float* Gp   = (const float*)d_in[4];
  const float* Up   = (const float*)d_in[5];
  const float* cart = (const float*)d_in[6];
  const int*   ridx = (const int*)d_in[7];
  float* out = (float*)d_out;
  unsigned short* hb = (unsigned short*)d_ws;

  const size_t PSZ = 4718592;
  f16* P0r = (f16*)(hb);
  f16* P0i = (f16*)(hb + PSZ);
  f16* P1r = (f16*)(hb + 2 * PSZ);
  f16* P1i = (f16*)(hb + 3 * PSZ);
  f16* xtr = (f16*)(hb + 4 * PSZ);
  f16* xti = (f16*)(hb + 4 * PSZ + 2097152);
  unsigned short* ut = hb + 4 * PSZ;
  unsigned short* yg = hb + 4 * PSZ + 2097152;
  unsigned short* partial = hb;

  const size_t HSZ = 8 * 32 * 36;

  k_transpose<<<dim3(128, 4), 256, 0, stream>>>(x, xtr, xti);
  k_vhm<<<dim3(32, 32), 256, 0, stream>>>(xtr, xti, P0r, P0i, Vp, Hp + 0 * HSZ);
  k_lay<1><<<dim3(32, 32), 256, 0, stream>>>(P0r, P0i, P1r, P1i, Hp + 1 * HSZ); // perm(l=4)
  k_lay<2><<<dim3(32, 32), 256, 0, stream>>>(P1r, P1i, P0r, P0i, Hp + 2 * HSZ); // perm(l=3)
  k_mgm<<<dim3(32, 32), 256, 0, stream>>>(P0r, P0i, P1r, P1i, Mp, Gp + 0 * HSZ);// switch+M+G1
  k_lay<4><<<dim3(32, 32), 256, 0, stream>>>(P1r, P1i, P0r, P0i, Gp + 1 * HSZ); // perm(l=2)
  k_lay<5><<<dim3(32, 32), 256, 0, stream>>>(P0r, P0i, P1r, P1i, Gp + 2 * HSZ); // perm(l=1)
  k_u<<<dim3(64, 64), 128, 0, stream>>>(P1r, P1i, ut, Up);                      // perm(l=0)
  k_gather<<<dim3(256), 256, 0, stream>>>(ut, ridx, yg);
  k_gemm2<<<dim3(G2_KC, 100), 256, 0, stream>>>(yg, cart, partial);
  k_reduce2<<<dim3(800), 256, 0, stream>>>(partial, out);
  (void)in_sizes; (void)n_in; (void)out_size; (void)ws_size;
}

// Round 11
// 308.610 us; speedup vs baseline: 1.1087x; 1.1087x over previous
//
#include <hip/hip_runtime.h>

// ---------------------------------------------------------------------------
// equinet F* pipeline on MI355X.
// R11: butterfly reverted to R9 (best known: 512-thr 4-group term-split).
// GEMM v3: A-staging removed from LDS (yg is L2-resident; A fragments load
// direct from global — A had zero cross-wave sharing so LDS buy was nil).
// LDS 55->18KB => ~4 blocks/CU, 800 blocks fit in ONE dispatch round.
// ---------------------------------------------------------------------------

typedef _Float16 f16;
typedef __attribute__((ext_vector_type(8))) short sx8;
typedef __attribute__((ext_vector_type(4))) float fx4;
typedef __attribute__((ext_vector_type(8))) unsigned short usx8;
typedef __attribute__((ext_vector_type(4))) unsigned short usx4;

__device__ __forceinline__ unsigned short f2bf(float f) {
  unsigned u = __builtin_bit_cast(unsigned, f);
  u = (u + 0x7FFFu + ((u >> 16) & 1u)) >> 16;
  return (unsigned short)u;
}
__device__ __forceinline__ float bf2f(unsigned short h) {
  return __builtin_bit_cast(float, ((unsigned)h) << 16);
}

template<int ID>
__device__ __forceinline__ int rp_apply(int k) {
  if constexpr (ID == 0) { return k; }
  else if constexpr (ID == 3) { return (k & 7) * 8 + (k >> 3); }
  else {
    constexpr int l = (ID == 1) ? 4 : (ID == 2) ? 3 : (ID == 4) ? 2 : (ID == 5) ? 1 : 0;
    constexpr int d = 1 << (5 - l);
    constexpr int m2 = 2 * d;
    int g = k / m2, r = k % m2;
    return g * m2 + (r & 1) * d + (r >> 1);
  }
}

__device__ __forceinline__ void term_decode(int t, int& lm, int& rm,
                                            bool& useXi, bool& toYi) {
  lm = (t < 2) ? t : (t < 4) ? (t + 4) : (t - 2);
  rm = (t >= 2 && t <= 5) ? (lm ^ 1) : lm;
  useXi = (t >= 4);
  toYi = (t >> 1) & 1;
}

#define SMEM_BYTES 36864

// ---------------------------------------------------------------------------
// Phase B helper (R9): one 6x6-block complex layer, terms split over 4 groups.
// ---------------------------------------------------------------------------
__device__ __forceinline__ void layer6(int g, int b, int P, int Q,
                                       const float* __restrict__ wp,
                                       const f16* ldsX, float* Y0, float* Y1,
                                       f16* __restrict__ yr,
                                       f16* __restrict__ yi) {
  int lm0, rm0, lm1, rm1;
  switch (g) {
    case 0:  lm0 = 0; rm0 = 0; lm1 = 1; rm1 = 1; break;
    case 1:  lm0 = 6; rm0 = 7; lm1 = 7; rm1 = 6; break;
    case 2:  lm0 = 2; rm0 = 3; lm1 = 3; rm1 = 2; break;
    default: lm0 = 4; rm0 = 4; lm1 = 5; rm1 = 5; break;
  }
  const int xbase = (g & 2) ? 36 : 0;
  float X[36], Y[36];
#pragma unroll
  for (int k = 0; k < 36; ++k) X[k] = (float)ldsX[(xbase + k) * 128 + b];
#pragma unroll
  for (int k = 0; k < 36; ++k) Y[k] = 0.f;

  for (int tt = 0; tt < 2; ++tt) {
    const int lm = tt ? lm1 : lm0;
    const int rm = tt ? rm1 : rm0;
    const float* Lw = wp + ((size_t)lm * 32 + P) * 36;
    const float* Rw = wp + ((size_t)rm * 32 + Q) * 36;
#pragma unroll
    for (int i = 0; i < 6; ++i) {
      float tk[6] = {0.f, 0.f, 0.f, 0.f, 0.f, 0.f};
#pragma unroll
      for (int j = 0; j < 6; ++j) {
        float xv = X[i * 6 + j];
#pragma unroll
        for (int k = 0; k < 6; ++k) tk[k] += xv * Rw[j * 6 + k];
      }
#pragma unroll
      for (int o = 0; o < 6; ++o) {
        float lv = Lw[i * 6 + o];
#pragma unroll
        for (int k = 0; k < 6; ++k) Y[o * 6 + k] += lv * tk[k];
      }
    }
  }
  __syncthreads();
  if (g == 2) {
#pragma unroll
    for (int k = 0; k < 36; ++k) Y0[k * 128 + b] = Y[k];
  } else if (g == 3) {
#pragma unroll
    for (int k = 0; k < 36; ++k) Y1[k * 128 + b] = Y[k];
  }
  __syncthreads();
  if (g == 0) {
#pragma unroll
    for (int k = 0; k < 36; ++k) {
      float v = Y[k] + Y0[k * 128 + b];
      yr[((size_t)((P * 6 + k / 6) * 192 + Q * 6 + k % 6)) * 128 + b] = (f16)v;
    }
  } else if (g == 1) {
#pragma unroll
    for (int k = 0; k < 36; ++k) {
      float v = Y[k] + Y1[k * 128 + b];
      yi[((size_t)((P * 6 + k / 6) * 192 + Q * 6 + k % 6)) * 128 + b] = (f16)v;
    }
  }
}

// ---------------------------------------------------------------------------
// Transpose x (B,128,128,2) fp32 -> xtr/xti (16384, 128) fp16
// ---------------------------------------------------------------------------
__global__ __launch_bounds__(256) void k_transpose(const float* __restrict__ x,
                                                   f16* __restrict__ xtr,
                                                   f16* __restrict__ xti) {
  __shared__ float ls[2][32][129];
  const int t = threadIdx.x;
  const int u = blockIdx.x;
  const int v0 = blockIdx.y * 32;
  for (int it = 0; it < 32; ++it) {
    int b = it * 4 + (t >> 6);
    int r = t & 63;
    int v = r >> 1, ch = r & 1;
    ls[ch][v][b] = x[(((size_t)b * 128 + u) * 128 + (v0 + v)) * 2 + ch];
  }
  __syncthreads();
  for (int it = 0; it < 32; ++it) {
    int idx = it * 256 + t;
    int ch = idx >> 12;
    int v = (idx >> 7) & 31;
    int b = idx & 127;
    f16* dst = ch ? xti : xtr;
    dst[((size_t)(u * 128 + v0 + v)) * 128 + b] = (f16)ls[ch][v][b];
  }
}

// ---------------------------------------------------------------------------
// V + H1 fused (R9). Phase A: group g computes V sub-block into LDS.
// ---------------------------------------------------------------------------
__global__ __launch_bounds__(512, 4) void k_vh(const f16* __restrict__ xtr,
                                               const f16* __restrict__ xti,
                                               f16* __restrict__ yr,
                                               f16* __restrict__ yi,
                                               const float* __restrict__ vp,
                                               const float* __restrict__ hp) {
  __shared__ __align__(16) char smem[SMEM_BYTES];
  f16* ldsX = (f16*)smem;
  float* Y0 = (float*)smem;
  float* Y1 = (float*)(smem + 18432);
  const int t = threadIdx.x;
  const int P = blockIdx.x, Q = blockIdx.y;
  const int g = __builtin_amdgcn_readfirstlane(t >> 7);
  const int b = t & 127;

  const int pp = g >> 1, qq = g & 1;
  const int p = 2 * P + pp, q = 2 * Q + qq;
  float Xr[4], Xi[4];
#pragma unroll
  for (int i = 0; i < 2; ++i)
#pragma unroll
    for (int j = 0; j < 2; ++j) {
      size_t off = ((size_t)((4 * P + 2 * pp + i) * 128 + (4 * Q + 2 * qq + j))) * 128 + b;
      Xr[i * 2 + j] = (float)xtr[off];
      Xi[i * 2 + j] = (float)xti[off];
    }
  float Ar[9], Ai[9];
#pragma unroll
  for (int k = 0; k < 9; ++k) { Ar[k] = 0.f; Ai[k] = 0.f; }
  for (int tt = 0; tt < 8; ++tt) {
    int lm, rm; bool useXi, toYi;
    term_decode(tt, lm, rm, useXi, toYi);
    const float* Lw = vp + ((size_t)lm * 64 + p) * 6;
    const float* Rw = vp + ((size_t)rm * 64 + q) * 6;
#pragma unroll
    for (int i = 0; i < 2; ++i) {
      float x0, x1;
      if (useXi) { x0 = Xi[i * 2 + 0]; x1 = Xi[i * 2 + 1]; }
      else       { x0 = Xr[i * 2 + 0]; x1 = Xr[i * 2 + 1]; }
      float t0 = x0 * Rw[0] + x1 * Rw[3];
      float t1 = x0 * Rw[1] + x1 * Rw[4];
      float t2 = x0 * Rw[2] + x1 * Rw[5];
      if (toYi) {
#pragma unroll
        for (int o = 0; o < 3; ++o) {
          float lv = Lw[i * 3 + o];
          Ai[o*3+0] += lv * t0; Ai[o*3+1] += lv * t1; Ai[o*3+2] += lv * t2;
        }
      } else {
#pragma unroll
        for (int o = 0; o < 3; ++o) {
          float lv = Lw[i * 3 + o];
          Ar[o*3+0] += lv * t0; Ar[o*3+1] += lv * t1; Ar[o*3+2] += lv * t2;
        }
      }
    }
  }
#pragma unroll
  for (int o = 0; o < 3; ++o)
#pragma unroll
    for (int k = 0; k < 3; ++k) {
      int ch = (3 * pp + o) * 6 + (3 * qq + k);
      ldsX[ch * 128 + b] = (f16)Ar[o * 3 + k];
      ldsX[(36 + ch) * 128 + b] = (f16)Ai[o * 3 + k];
    }
  __syncthreads();
  layer6(g, b, P, Q, hp, ldsX, Y0, Y1, yr, yi);
}

// ---------------------------------------------------------------------------
// H/G layer (R9): staged copy + term-split.
// ---------------------------------------------------------------------------
template<int PERM>
__global__ __launch_bounds__(512, 4) void k_hg(const f16* __restrict__ xr,
                                               const f16* __restrict__ xi,
                                               f16* __restrict__ yr,
                                               f16* __restrict__ yi,
                                               const float* __restrict__ wp) {
  __shared__ __align__(16) char smem[SMEM_BYTES];
  f16* ldsX = (f16*)smem;
  float* Y0 = (float*)smem;
  float* Y1 = (float*)(smem + 18432);
  const int t = threadIdx.x;
  const int P = blockIdx.x, Q = blockIdx.y;

  for (int r = 0; r < 3; ++r) {
    int idx = t + r * 512;
    if (idx < 1152) {
      int c = idx >> 4, o8 = (idx & 15) * 8;
      int cc = (c < 36) ? c : c - 36;
      int I = cc / 6, J = cc % 6;
      int grow = rp_apply<PERM>(2 * P + I / 3) * 3 + I % 3;
      int gcol = rp_apply<PERM>(2 * Q + J / 3) * 3 + J % 3;
      const f16* src = (c < 36) ? xr : xi;
      usx8 v = *(const usx8*)(src + ((size_t)(grow * 192 + gcol)) * 128 + o8);
      *(usx8*)(ldsX + c * 128 + o8) = v;
    }
  }
  __syncthreads();
  const int g = __builtin_amdgcn_readfirstlane(t >> 7);
  const int b = t & 127;
  layer6(g, b, P, Q, wp, ldsX, Y0, Y1, yr, yi);
}

// ---------------------------------------------------------------------------
// switch + M1..M3 + G1 (R9).
// ---------------------------------------------------------------------------
__global__ __launch_bounds__(512, 4) void k_mg(const f16* __restrict__ xr,
                                               const f16* __restrict__ xi,
                                               f16* __restrict__ yr,
                                               f16* __restrict__ yi,
                                               const float* __restrict__ mp,
                                               const float* __restrict__ gp) {
  __shared__ __align__(16) char smem[SMEM_BYTES];
  f16* ldsX = (f16*)smem;
  float* Y0 = (float*)smem;
  float* Y1 = (float*)(smem + 18432);
  const int t = threadIdx.x;
  const int P = blockIdx.x, Q = blockIdx.y;
  const int g = __builtin_amdgcn_readfirstlane(t >> 7);
  const int b = t & 127;

  const int aa = g >> 1, bb = g & 1;
  const int p = 2 * P + aa, q = 2 * Q + bb;
  const int prow = rp_apply<3>(p) * 3, pcol = rp_apply<3>(q) * 3;
  float Xr[9], Xi[9];
#pragma unroll
  for (int i = 0; i < 3; ++i)
#pragma unroll
    for (int j = 0; j < 3; ++j) {
      size_t off = ((size_t)((prow + i) * 192 + (pcol + j))) * 128 + b;
      Xr[i * 3 + j] = (float)xr[off];
      Xi[i * 3 + j] = (float)xi[off];
    }
  for (int lk = 0; lk < 3; ++lk) {
    const float* wp = mp + (size_t)lk * (8 * 64 * 9);
    float Yr9[9], Yi9[9];
#pragma unroll
    for (int k = 0; k < 9; ++k) { Yr9[k] = Xr[k]; Yi9[k] = Xi[k]; }
    for (int tt = 0; tt < 8; ++tt) {
      int lm, rm; bool useXi, toYi;
      term_decode(tt, lm, rm, useXi, toYi);
      const float* Lw = wp + ((size_t)lm * 64 + p) * 9;
      const float* Rw = wp + ((size_t)rm * 64 + q) * 9;
#pragma unroll
      for (int i = 0; i < 3; ++i) {
        float x0, x1, x2;
        if (useXi) { x0 = Xi[i*3+0]; x1 = Xi[i*3+1]; x2 = Xi[i*3+2]; }
        else       { x0 = Xr[i*3+0]; x1 = Xr[i*3+1]; x2 = Xr[i*3+2]; }
        float t0 = x0 * Rw[0] + x1 * Rw[3] + x2 * Rw[6];
        float t1 = x0 * Rw[1] + x1 * Rw[4] + x2 * Rw[7];
        float t2 = x0 * Rw[2] + x1 * Rw[5] + x2 * Rw[8];
        if (toYi) {
#pragma unroll
          for (int o = 0; o < 3; ++o) {
            float lv = Lw[i * 3 + o];
            Yi9[o*3+0] += lv * t0; Yi9[o*3+1] += lv * t1; Yi9[o*3+2] += lv * t2;
          }
        } else {
#pragma unroll
          for (int o = 0; o < 3; ++o) {
            float lv = Lw[i * 3 + o];
            Yr9[o*3+0] += lv * t0; Yr9[o*3+1] += lv * t1; Yr9[o*3+2] += lv * t2;
          }
        }
      }
    }
#pragma unroll
    for (int k = 0; k < 9; ++k) { Xr[k] = Yr9[k]; Xi[k] = Yi9[k]; }
  }
#pragma unroll
  for (int i = 0; i < 3; ++i)
#pragma unroll
    for (int j = 0; j < 3; ++j) {
      int ch = (3 * aa + i) * 6 + (3 * bb + j);
      ldsX[ch * 128 + b] = (f16)Xr[i * 3 + j];
      ldsX[(36 + ch) * 128 + b] = (f16)Xi[i * 3 + j];
    }
  __syncthreads();
  layer6(g, b, P, Q, gp, ldsX, Y0, Y1, yr, yi);
}

// ---------------------------------------------------------------------------
// U layer (R9). perm(l=0) on read. Up:(8,64,3,2)
// ---------------------------------------------------------------------------
__global__ __launch_bounds__(128, 2) void k_u(const f16* __restrict__ xr,
                                              const f16* __restrict__ xi,
                                              unsigned short* __restrict__ ut,
                                              const float* __restrict__ wp) {
  const int b = threadIdx.x;
  const int p = blockIdx.x, q = blockIdx.y;
  int rrow[3], rcol[3];
#pragma unroll
  for (int i = 0; i < 3; ++i) {
    rrow[i] = rp_apply<6>(p) * 3 + i;
    rcol[i] = rp_apply<6>(q) * 3 + i;
  }
  float X[9], Y[4] = {0.f, 0.f, 0.f, 0.f};
  auto loadX = [&](const f16* src) {
#pragma unroll
    for (int i = 0; i < 3; ++i)
#pragma unroll
      for (int j = 0; j < 3; ++j)
        X[i * 3 + j] = (float)src[((size_t)(rrow[i] * 192 + rcol[j])) * 128 + b];
  };
  auto term = [&](int lm, int rm) {
    const float* Lw = wp + ((size_t)lm * 64 + p) * 6;
    const float* Rw = wp + ((size_t)rm * 64 + q) * 6;
#pragma unroll
    for (int i = 0; i < 3; ++i) {
      float t0 = X[i*3+0] * Rw[0] + X[i*3+1] * Rw[2] + X[i*3+2] * Rw[4];
      float t1 = X[i*3+0] * Rw[1] + X[i*3+1] * Rw[3] + X[i*3+2] * Rw[5];
      Y[0] += Lw[i*2+0] * t0; Y[1] += Lw[i*2+0] * t1;
      Y[2] += Lw[i*2+1] * t0; Y[3] += Lw[i*2+1] * t1;
    }
  };
  loadX(xr); term(0, 0); term(3, 3);
  loadX(xi); term(4, 5); term(7, 6);
#pragma unroll
  for (int o = 0; o < 2; ++o)
#pragma unroll
    for (int k = 0; k < 2; ++k)
      ut[((size_t)((p * 2 + o) * 128 + (q * 2 + k))) * 128 + b] = f2bf(Y[o * 2 + k]);
}

// ---------------------------------------------------------------------------
// Gather + transpose (R9)
// ---------------------------------------------------------------------------
__global__ __launch_bounds__(256) void k_gather(const unsigned short* __restrict__ ut,
                                                const int* __restrict__ r_index,
                                                unsigned short* __restrict__ yg) {
  __shared__ unsigned short ls[64][130];
  __shared__ int ridx[64];
  const int t = threadIdx.x;
  const int m0 = blockIdx.x * 64;
  if (t < 64) ridx[t] = r_index[m0 + t];
  __syncthreads();
  for (int it = 0; it < 32; ++it) {
    int idx = it * 256 + t;
    int ml = idx >> 7, b = idx & 127;
    ls[ml][b] = ut[(size_t)ridx[ml] * 128 + b];
  }
  __syncthreads();
  int b = t >> 1, half = t & 1;
#pragma unroll
  for (int c = 0; c < 4; ++c) {
    usx8 v;
#pragma unroll
    for (int e = 0; e < 8; ++e) v[e] = ls[half * 32 + c * 8 + e][b];
    *(usx8*)(yg + (size_t)b * 16384 + m0 + half * 32 + c * 8) = v;
  }
}

// ---------------------------------------------------------------------------
// GEMM v3: B-only LDS double-buffer; A fragments direct from global (yg is
// L2-resident, no cross-wave A sharing). Grid (8,100), BK=64, bf16 partial.
// ---------------------------------------------------------------------------
#define G3_KC 8
#define G3_STEPS 32
#define G3_PITCH 72

__global__ __launch_bounds__(256) void k_gemm3(const unsigned short* __restrict__ yg,
                                               const float* __restrict__ cart,
                                               unsigned short* __restrict__ partial) {
  __shared__ unsigned short Bs[2][64][G3_PITCH];   // 18.4 KB
  const int t = threadIdx.x;
  const int lane = t & 63, w = t >> 6;
  const int kc = blockIdx.x;
  const int c0 = blockIdx.y * 64;
  const int k0 = kc * 2048;

  fx4 acc[2][4];
#pragma unroll
  for (int i = 0; i < 2; ++i)
#pragma unroll
    for (int j = 0; j < 4; ++j) acc[i][j] = (fx4)0.f;

  // per-lane A base: rows w*32+(lane&15)(+16 for mi=1), k window (lane>>4)*8
  const unsigned short* aBase = yg + (size_t)(w * 32 + (lane & 15)) * 16384
                                   + k0 + (lane >> 4) * 8;

  auto ldB = [&](int rep, int kpos, fx4* f0, fx4* f1) {
    int c = t + rep * 256;
    const float* p = cart + (size_t)(c0 + (c >> 3)) * 16384 + kpos + (c & 7) * 8;
    *f0 = *(const fx4*)p;
    *f1 = *(const fx4*)(p + 4);
  };
  auto stB = [&](int buf, int rep, fx4 f0, fx4 f1) {
    int c = t + rep * 256;
    usx8 v;
    v[0]=f2bf(f0[0]); v[1]=f2bf(f0[1]); v[2]=f2bf(f0[2]); v[3]=f2bf(f0[3]);
    v[4]=f2bf(f1[0]); v[5]=f2bf(f1[1]); v[6]=f2bf(f1[2]); v[7]=f2bf(f1[3]);
    *(usx8*)(&Bs[buf][c >> 3][(c & 7) * 8]) = v;
  };

  {
    fx4 b00, b01, b10, b11;
    ldB(0, k0, &b00, &b01); ldB(1, k0, &b10, &b11);
    stB(0, 0, b00, b01); stB(0, 1, b10, b11);
  }
  __syncthreads();

  for (int s = 0; s < G3_STEPS; ++s) {
    const int cur = s & 1;
    fx4 b00, b01, b10, b11;
    const bool pf = (s + 1 < G3_STEPS);
    if (pf) {
      int kpos = k0 + (s + 1) * 64;
      ldB(0, kpos, &b00, &b01); ldB(1, kpos, &b10, &b11);
    }
    // A fragments direct from global (L2-hit)
    sx8 af[2][2], bf[4][2];
#pragma unroll
    for (int mi = 0; mi < 2; ++mi)
#pragma unroll
      for (int kk = 0; kk < 2; ++kk)
        af[mi][kk] = *(const sx8*)(aBase + (size_t)mi * 16 * 16384 + s * 64 + kk * 32);
#pragma unroll
    for (int ni = 0; ni < 4; ++ni)
#pragma unroll
      for (int kk = 0; kk < 2; ++kk)
        bf[ni][kk] = *(const sx8*)(&Bs[cur][ni * 16 + (lane & 15)][kk * 32 + (lane >> 4) * 8]);
#pragma unroll
    for (int kk = 0; kk < 2; ++kk)
#pragma unroll
      for (int mi = 0; mi < 2; ++mi)
#pragma unroll
        for (int ni = 0; ni < 4; ++ni)
          acc[mi][ni] = __builtin_amdgcn_mfma_f32_16x16x32_bf16(af[mi][kk], bf[ni][kk], acc[mi][ni], 0, 0, 0);
    if (pf) {
      stB(cur ^ 1, 0, b00, b01); stB(cur ^ 1, 1, b10, b11);
    }
    __syncthreads();
  }

  // epilogue: partial[kc][b][c] bf16
#pragma unroll
  for (int mi = 0; mi < 2; ++mi) {
    int brow = w * 32 + mi * 16 + (lane >> 4) * 4;
#pragma unroll
    for (int ni = 0; ni < 4; ++ni) {
      int cc = c0 + ni * 16 + (lane & 15);
#pragma unroll
      for (int r = 0; r < 4; ++r)
        partial[((size_t)kc * 128 + brow + r) * 6400 + cc] = f2bf(acc[mi][ni][r]);
    }
  }
}

__global__ __launch_bounds__(256) void k_reduce2(const unsigned short* __restrict__ partial,
                                                 float* __restrict__ out) {
  int i = blockIdx.x * 256 + threadIdx.x;
  fx4 s = (fx4)0.f;
#pragma unroll
  for (int kc = 0; kc < G3_KC; ++kc) {
    usx4 v = *(const usx4*)(partial + (size_t)kc * 819200 + (size_t)i * 4);
    s[0] += bf2f(v[0]); s[1] += bf2f(v[1]); s[2] += bf2f(v[2]); s[3] += bf2f(v[3]);
  }
  *(fx4*)(out + (size_t)i * 4) = s;
}

// ---------------------------------------------------------------------------
extern "C" void kernel_launch(void* const* d_in, const int* in_sizes, int n_in,
                              void* d_out, int out_size, void* d_ws, size_t ws_size,
                              hipStream_t stream) {
  const float* x    = (const float*)d_in[0];
  const float* Vp   = (const float*)d_in[1];
  const float* Hp   = (const float*)d_in[2];
  const float* Mp   = (const float*)d_in[3];
  const float* Gp   = (const float*)d_in[4];
  const float* Up   = (const float*)d_in[5];
  const float* cart = (const float*)d_in[6];
  const int*   ridx = (const int*)d_in[7];
  float* out = (float*)d_out;
  unsigned short* hb = (unsigned short*)d_ws;

  const size_t PSZ = 4718592;
  f16* P0r = (f16*)(hb);
  f16* P0i = (f16*)(hb + PSZ);
  f16* P1r = (f16*)(hb + 2 * PSZ);
  f16* P1i = (f16*)(hb + 3 * PSZ);
  f16* xtr = (f16*)(hb + 4 * PSZ);
  f16* xti = (f16*)(hb + 4 * PSZ + 2097152);
  unsigned short* ut = hb + 4 * PSZ;
  unsigned short* yg = hb + 4 * PSZ + 2097152;
  unsigned short* partial = hb;

  const size_t HSZ = 8 * 32 * 36;

  k_transpose<<<dim3(128, 4), 256, 0, stream>>>(x, xtr, xti);
  k_vh<<<dim3(32, 32), 512, 0, stream>>>(xtr, xti, P0r, P0i, Vp, Hp + 0 * HSZ);
  k_hg<1><<<dim3(32, 32), 512, 0, stream>>>(P0r, P0i, P1r, P1i, Hp + 1 * HSZ);  // perm(l=4)
  k_hg<2><<<dim3(32, 32), 512, 0, stream>>>(P1r, P1i, P0r, P0i, Hp + 2 * HSZ);  // perm(l=3)
  k_mg<<<dim3(32, 32), 512, 0, stream>>>(P0r, P0i, P1r, P1i, Mp, Gp + 0 * HSZ); // switch+M123+G1
  k_hg<4><<<dim3(32, 32), 512, 0, stream>>>(P1r, P1i, P0r, P0i, Gp + 1 * HSZ);  // perm(l=2)
  k_hg<5><<<dim3(32, 32), 512, 0, stream>>>(P0r, P0i, P1r, P1i, Gp + 2 * HSZ);  // perm(l=1)
  k_u<<<dim3(64, 64), 128, 0, stream>>>(P1r, P1i, ut, Up);                      // perm(l=0) inside
  k_gather<<<dim3(256), 256, 0, stream>>>(ut, ridx, yg);
  k_gemm3<<<dim3(G3_KC, 100), 256, 0, stream>>>(yg, cart, partial);
  k_reduce2<<<dim3(800), 256, 0, stream>>>(partial, out);
  (void)in_sizes; (void)n_in; (void)out_size; (void)ws_size;
}